// Round 16
// baseline (1161.095 us; speedup 1.0000x reference)
//
#include <hip/hip_runtime.h>
#include <hip/hip_bf16.h>

typedef __attribute__((ext_vector_type(8))) short short8_t;
typedef __attribute__((ext_vector_type(4))) float f32x4;
typedef __attribute__((ext_vector_type(4))) unsigned int u32x4;

#define KINST 100000
#define KPAD  100096   // 782 * 128 = 1564 * 64
#define DIMIN 768
#define DIMEMB 512
#define DIMATTN 384

__device__ __forceinline__ unsigned short f2bf(float f) {
    unsigned int u = __builtin_bit_cast(unsigned int, f);
    u = u + 0x7FFFu + ((u >> 16) & 1u);       // RNE
    return (unsigned short)(u >> 16);
}
__device__ __forceinline__ unsigned int packbf(float a, float b) {
    return (unsigned int)f2bf(a) | ((unsigned int)f2bf(b) << 16);
}
__device__ __forceinline__ float bf2f(unsigned short h) {
    unsigned int u = ((unsigned int)h) << 16;
    return __builtin_bit_cast(float, u);
}
__device__ __forceinline__ float fast_tanh(float x) {
    const float e2 = __expf(2.f * x);
    return (e2 - 1.f) * __builtin_amdgcn_rcpf(e2 + 1.f);
}
// async global->LDS, 16B per lane. LDS dest must be wave-uniform base + lane*16.
__device__ __forceinline__ void gll16(const unsigned short* g, unsigned short* l) {
    __builtin_amdgcn_global_load_lds(
        (const __attribute__((address_space(1))) unsigned int*)g,
        (__attribute__((address_space(3))) unsigned int*)l, 16, 0, 0);
}

// ---------------- prep (R9 verified) ----------------
// WpTt (PLAIN): [t<24][n<512][c<4][e<8] = bf16(Wproj[(t*32+c*8+e)*512 + n])
// W1Ts (SWIZZLED): [t<8][n<384][cs<8][e<8], cs = c ^ (n&7) = bf16(W1[(t*64+c*8+e)*384 + n])
__global__ __launch_bounds__(256) void k_prep(
    const float* __restrict__ Wproj, const float* __restrict__ W1,
    unsigned short* __restrict__ WpTt, unsigned short* __restrict__ W1Ts)
{
    const int idx = blockIdx.x * 256 + threadIdx.x;
    if (idx < 49152) {                 // 24*512*4
        const int t = idx >> 11, r = idx & 2047;
        const int n = r >> 2, c = r & 3;
        short8_t v;
        #pragma unroll
        for (int e = 0; e < 8; ++e)
            v[e] = (short)f2bf(Wproj[(size_t)(t * 32 + c * 8 + e) * DIMEMB + n]);
        *(short8_t*)&WpTt[t * 16384 + n * 32 + c * 8] = v;
    } else {
        const int j = idx - 49152;     // < 24576 = 8*8*384
        const int t = j / 3072, r = j % 3072;
        const int c = r / 384, n = r % 384;
        short8_t v;
        #pragma unroll
        for (int e = 0; e < 8; ++e)
            v[e] = (short)f2bf(W1[(size_t)(t * 64 + c * 8 + e) * DIMATTN + n]);
        *(short8_t*)&W1Ts[t * 24576 + n * 64 + ((c ^ (n & 7)) << 3)] = v;
    }
}

// ---------------- GEMM1: H = relu(X @ Wp + b); BM=64, BN=512, BK=32 ----------------
// R9-verified structure (191 us), now at 3 blocks/CU for barrier-group decorrelation.
// H stored SWIZZLED (R4/R9 format): row*512 + (col>>6)*64 + ((((col>>3)&7)^(row&7))<<3) + (col&7)
__global__ __launch_bounds__(256, 3) void k_gemm1(
    const float* __restrict__ X,
    const unsigned short* __restrict__ WpTt,
    const float* __restrict__ bproj,
    unsigned short* __restrict__ H)
{
    __shared__ unsigned short As[2][2048];   // 64 rows x 32 bf16, granule-XOR
    const int tid = threadIdx.x;
    const int lane = tid & 63, w = tid >> 6;   // 4 waves; wave w -> cols w*128..+127
    const int g = lane >> 4, fr = lane & 15;
    const int brow = blockIdx.x * 64;

    // A staging: thread -> row tid>>2 (0..63), k-granule tid&3 (8 fp32 = 32B), coalesced
    const int arow = tid >> 2, aq4 = tid & 3;
    int agr = brow + arow; if (agr >= KINST) agr = KINST - 1;
    const float* xsrc = X + (size_t)agr * DIMIN + aq4 * 8;
    const int awoff = arow * 32 + ((aq4 ^ ((arow >> 1) & 3)) << 3);
    const int aro = (g ^ ((fr >> 1) & 3)) << 3;   // frag read slot (verified, 0 conflicts)

    // B: per-lane frag base; frag j at + j*512; step t at + t*16384
    const unsigned short* gB = WpTt + (size_t)(w * 128 + fr) * 32 + g * 8;

    f32x4 acc[4][8] = {};
    short8_t Bf[2][8];
    float4 xva, xvb;

    // ---- prologue: X(0)->As[0]; B(0)->Bf[0]; X(1)->regs ----
    {
        float4 xa = *(const float4*)(xsrc);
        float4 xb = *(const float4*)(xsrc + 4);
        #pragma unroll
        for (int j = 0; j < 8; ++j)
            Bf[0][j] = *(const short8_t*)(gB + j * 512);
        xva = *(const float4*)(xsrc + 32);
        xvb = *(const float4*)(xsrc + 36);
        u32x4 p;
        p[0] = packbf(xa.x, xa.y); p[1] = packbf(xa.z, xa.w);
        p[2] = packbf(xb.x, xb.y); p[3] = packbf(xb.z, xb.w);
        *(u32x4*)&As[0][awoff] = p;
    }
    asm volatile("s_waitcnt lgkmcnt(0)" ::: "memory");
    __builtin_amdgcn_sched_barrier(0);
    __builtin_amdgcn_s_barrier();
    __builtin_amdgcn_sched_barrier(0);

#define G1STEP(P, T)                                                           \
    {                                                                          \
        if ((T) < 23) {   /* issue B(T+1) -> Bf[P^1]; consumed NEXT step */    \
            const unsigned short* gBt = gB + (size_t)((T) + 1) * 16384;        \
            _Pragma("unroll")                                                  \
            for (int j = 0; j < 8; ++j)                                        \
                Bf[(P) ^ 1][j] = *(const short8_t*)(gBt + j * 512);            \
        }                                                                      \
        short8_t af[4];   /* A frags from As[P] (ds_read) */                   \
        _Pragma("unroll")                                                      \
        for (int i = 0; i < 4; ++i)                                            \
            af[i] = *(const short8_t*)&As[P][(i * 16 + fr) * 32 + aro];        \
        if ((T) < 23) {   /* convert X(T+1) -> As[P^1]; implicit vmcnt wait    \
                             here also retires B(T) (FIFO) */                  \
            u32x4 p;                                                           \
            p[0] = packbf(xva.x, xva.y); p[1] = packbf(xva.z, xva.w);          \
            p[2] = packbf(xvb.x, xvb.y); p[3] = packbf(xvb.z, xvb.w);          \
            *(u32x4*)&As[(P) ^ 1][awoff] = p;                                  \
        }                                                                      \
        if ((T) < 22) {   /* issue X(T+2); rides the barrier */                \
            xva = *(const float4*)(xsrc + ((T) + 2) * 32);                     \
            xvb = *(const float4*)(xsrc + ((T) + 2) * 32 + 4);                 \
        }                                                                      \
        asm volatile("s_waitcnt lgkmcnt(0)" ::: "memory");                     \
        __builtin_amdgcn_sched_barrier(0);                                     \
        __builtin_amdgcn_s_barrier();                                          \
        __builtin_amdgcn_sched_barrier(0);                                     \
        __builtin_amdgcn_s_setprio(1);                                        \
        _Pragma("unroll")                                                      \
        for (int j = 0; j < 8; ++j)                                            \
            _Pragma("unroll")                                                  \
            for (int i = 0; i < 4; ++i)                                        \
                acc[i][j] = __builtin_amdgcn_mfma_f32_16x16x32_bf16(           \
                    af[i], Bf[P][j], acc[i][j], 0, 0, 0);                      \
        __builtin_amdgcn_s_setprio(0);                                        \
    }

    for (int tt = 0; tt < 24; tt += 2) {
        G1STEP(0, tt);
        G1STEP(1, tt + 1);
    }
#undef G1STEP

    // ---- epilogue: bias + relu, SWIZZLED bf16 H store ----
    #pragma unroll
    for (int j = 0; j < 8; ++j) {
        const int col = w * 128 + j * 16 + fr;
        const float bias = bproj[col];
        const int tile = (col >> 6) << 6, cc = (col >> 3) & 7, lo = col & 7;
        #pragma unroll
        for (int i = 0; i < 4; ++i) {
            const int rb = brow + i * 16 + g * 4;
            #pragma unroll
            for (int r = 0; r < 4; ++r) {
                const int row = rb + r;
                const float v = fmaxf(acc[i][j][r] + bias, 0.f);
                H[(size_t)row * DIMEMB + tile + ((cc ^ (row & 7)) << 3) + lo] =
                    (row < KINST) ? f2bf(v) : (unsigned short)0;
            }
        }
    }
}

// -------- GEMM2 partial scores (R4/R9 verified, swizzled H) --------
__global__ __launch_bounds__(256) void k_gemm2(
    const unsigned short* __restrict__ H,
    const unsigned short* __restrict__ W1Ts,
    const float* __restrict__ b1,
    const float* __restrict__ W2,
    float* __restrict__ Tpart)
{
    __shared__ unsigned short As[2][8192];
    __shared__ unsigned short Bs[2][8192];
    __shared__ float sred[2][128];
    const int tid = threadIdx.x;
    const int lane = tid & 63, w = tid >> 6;
    const int wr = w >> 1, wc = w & 1;
    const int g = lane >> 4, fr = lane & 15;
    const int cb = blockIdx.x;               // 0..2
    const int brow = blockIdx.y * 128;
    const int bcol = cb * 128;

    const unsigned short* gA = H + (size_t)(brow + w * 32 + (lane >> 3)) * DIMEMB + (lane & 7) * 8;
    const unsigned short* gB = W1Ts + (size_t)(bcol + w * 32 + (lane >> 3)) * 64 + (lane & 7) * 8;
    const int loff = w * 2048 + lane * 8;

    f32x4 acc[4][4] = {};

    #pragma unroll
    for (int q = 0; q < 4; ++q) {
        gll16(gA + q * 4096, &As[0][loff + q * 512]);
        gll16(gB + q * 512,  &Bs[0][loff + q * 512]);
    }
    __syncthreads();

    for (int t = 0; t < 8; ++t) {
        const int buf = t & 1;
        if (t < 7) {
            #pragma unroll
            for (int q = 0; q < 4; ++q) {
                gll16(gA + (t + 1) * 64 + q * 4096,           &As[buf ^ 1][loff + q * 512]);
                gll16(gB + (size_t)(t + 1) * 24576 + q * 512, &Bs[buf ^ 1][loff + q * 512]);
            }
        }
        __builtin_amdgcn_s_setprio(1);
        #pragma unroll
        for (int kk = 0; kk < 2; ++kk) {
            short8_t af[4];
            #pragma unroll
            for (int i = 0; i < 4; ++i) {
                const int row = wr * 64 + i * 16 + fr;
                af[i] = *(const short8_t*)&As[buf][row * 64 + (((kk * 4 + g) ^ (fr & 7)) << 3)];
            }
            #pragma unroll
            for (int j = 0; j < 4; ++j) {
                const int rowb = wc * 64 + j * 16 + fr;
                const short8_t bf = *(const short8_t*)&Bs[buf][rowb * 64 + (((kk * 4 + g) ^ (fr & 7)) << 3)];
                #pragma unroll
                for (int i = 0; i < 4; ++i)
                    acc[i][j] = __builtin_amdgcn_mfma_f32_16x16x32_bf16(af[i], bf, acc[i][j], 0, 0, 0);
            }
        }
        __builtin_amdgcn_s_setprio(0);
        if (t < 7) __syncthreads();
    }

    float ps[4][4] = {};
    #pragma unroll
    for (int j = 0; j < 4; ++j) {
        const int col = bcol + wc * 64 + j * 16 + fr;
        const float bb = b1[col], ww = W2[col];
        #pragma unroll
        for (int i = 0; i < 4; ++i)
            #pragma unroll
            for (int r = 0; r < 4; ++r)
                ps[i][r] += fast_tanh(acc[i][j][r] + bb) * ww;
    }
    #pragma unroll
    for (int off = 1; off < 16; off <<= 1)
        #pragma unroll
        for (int i = 0; i < 4; ++i)
            #pragma unroll
            for (int r = 0; r < 4; ++r)
                ps[i][r] += __shfl_xor(ps[i][r], off, 64);
    if (fr == 0) {
        #pragma unroll
        for (int i = 0; i < 4; ++i)
            #pragma unroll
            for (int r = 0; r < 4; ++r)
                sred[wc][wr * 64 + i * 16 + g * 4 + r] = ps[i][r];
    }
    __syncthreads();
    if (tid < 128)
        Tpart[(size_t)cb * KPAD + brow + tid] = sred[0][tid] + sred[1][tid];
}

// ---------------- poolE (R4/R9 verified, swizzled H) ----------------
__global__ __launch_bounds__(512) void k_poolE(
    const float* __restrict__ Tpart,
    const unsigned short* __restrict__ H,
    const float* __restrict__ b2,
    float* __restrict__ Spart,
    float* __restrict__ Mpart)
{
    __shared__ float Elds[1024];
    __shared__ float red[8][512];
    __shared__ float ssum[8];
    const int tid = threadIdx.x, lane = tid & 63, w = tid >> 6;
    const int base = blockIdx.x * 1024;
    const float bb = b2[0];
    float es = 0.f;
    #pragma unroll
    for (int u = 0; u < 2; ++u) {
        const int r = base + u * 512 + tid;
        float e = 0.f;
        if (r < KINST)
            e = __expf(Tpart[r] + Tpart[KPAD + r] + Tpart[2 * KPAD + r] + bb);
        Elds[u * 512 + tid] = e;
        es += e;
    }
    #pragma unroll
    for (int off = 1; off < 64; off <<= 1) es += __shfl_xor(es, off, 64);
    if (lane == 0) ssum[w] = es;
    __syncthreads();
    if (tid == 0) {
        float t = 0.f;
        #pragma unroll
        for (int i = 0; i < 8; ++i) t += ssum[i];
        Spart[blockIdx.x] = t;
    }

    float pa[8] = {};
    const int tile = (lane >> 3) << 6, cf = lane & 7;
    for (int i = 0; i < 128; ++i) {
        const int lr = i * 8 + w;
        const float e = Elds[lr];
        if (e != 0.f) {                       // wave-uniform; guards OOB rows
            const int r = base + lr;
            const short8_t v = *(const short8_t*)(H + (size_t)r * DIMEMB + tile + ((cf ^ (r & 7)) << 3));
            #pragma unroll
            for (int j = 0; j < 8; ++j) pa[j] += e * bf2f((unsigned short)v[j]);
        }
    }
    #pragma unroll
    for (int j = 0; j < 8; ++j) red[w][lane * 8 + j] = pa[j];
    __syncthreads();
    float s2 = 0.f;
    #pragma unroll
    for (int k = 0; k < 8; ++k) s2 += red[k][tid];
    Mpart[(size_t)blockIdx.x * DIMEMB + tid] = s2;
}

// ---------------- head (R4/R9 verified) ----------------
__global__ __launch_bounds__(512) void k_head(
    const float* __restrict__ Spart,   // [98]
    const float* __restrict__ Mpart,   // [98][512]
    const float* __restrict__ Wr,      // [512][13]
    const float* __restrict__ Xtfl,    // [13][512]
    const float* __restrict__ Wp,      // [512][2]
    const float* __restrict__ bp,      // [2]
    float* __restrict__ outp)
{
    __shared__ float Mlds[512];
    __shared__ float logits[13];
    __shared__ float wsel[5];
    __shared__ int isel[5];
    __shared__ float Slds;
    __shared__ float swred[8];
    __shared__ float r0s[8], r1s[8];
    const int tid = threadIdx.x, lane = tid & 63, w = tid >> 6;

    float s = 0.f;
    if (tid < 98) s = Spart[tid];
    #pragma unroll
    for (int off = 1; off < 64; off <<= 1) s += __shfl_xor(s, off, 64);
    if (lane == 0) swred[w] = s;

    float m = 0.f;
    #pragma unroll 2
    for (int b = 0; b < 98; ++b) m += Mpart[(size_t)b * 512 + tid];

    __syncthreads();
    if (tid == 0) {
        float t = 0.f;
        #pragma unroll
        for (int i = 0; i < 8; ++i) t += swred[i];
        Slds = t;
    }
    __syncthreads();
    Mlds[tid] = m / Slds;
    __syncthreads();
    if (tid < 13) {
        float l = 0.f;
        for (int dd = 0; dd < 512; ++dd) l += Mlds[dd] * Wr[dd * 13 + tid];
        logits[tid] = l;
    }
    __syncthreads();
    if (tid == 0) {
        float mx = -1e30f;
        for (int i = 0; i < 13; ++i) mx = fmaxf(mx, logits[i]);
        float pe[13]; float sum = 0.f;
        for (int i = 0; i < 13; ++i) { pe[i] = __expf(logits[i] - mx); sum += pe[i]; }
        unsigned used = 0;
        for (int t = 0; t < 5; ++t) {
            int bi = 0; float bv = -1.f;
            for (int i = 0; i < 13; ++i)
                if (!((used >> i) & 1u) && pe[i] > bv) { bv = pe[i]; bi = i; }
            used |= (1u << bi);
            wsel[t] = bv / sum;
            isel[t] = bi;
        }
    }
    __syncthreads();
    float mo = 0.f;
    #pragma unroll
    for (int t = 0; t < 5; ++t) mo += wsel[t] * Xtfl[isel[t] * 512 + tid];
    float p0 = mo * Wp[tid * 2 + 0];
    float p1 = mo * Wp[tid * 2 + 1];
    #pragma unroll
    for (int off = 1; off < 64; off <<= 1) {
        p0 += __shfl_xor(p0, off, 64);
        p1 += __shfl_xor(p1, off, 64);
    }
    if (lane == 0) { r0s[w] = p0; r1s[w] = p1; }
    __syncthreads();
    if (tid == 0) {
        float a = bp[0], b = bp[1];
        for (int i = 0; i < 8; ++i) { a += r0s[i]; b += r1s[i]; }
        outp[0] = a; outp[1] = b;
    }
}

extern "C" void kernel_launch(void* const* d_in, const int* in_sizes, int n_in,
                              void* d_out, int out_size, void* d_ws, size_t ws_size,
                              hipStream_t stream)
{
    const float* Xtfl  = (const float*)d_in[0];
    const float* X     = (const float*)d_in[1];
    const float* Wproj = (const float*)d_in[2];
    const float* bproj = (const float*)d_in[3];
    const float* W1    = (const float*)d_in[4];
    const float* b1    = (const float*)d_in[5];
    const float* W2    = (const float*)d_in[6];
    const float* b2    = (const float*)d_in[7];
    const float* Wr    = (const float*)d_in[8];
    const float* Wp    = (const float*)d_in[9];
    const float* bp    = (const float*)d_in[10];
    float* out = (float*)d_out;

    // ws layout (~105 MiB total)
    char* ws = (char*)d_ws;
    size_t off = 0;
    unsigned short* H    = (unsigned short*)(ws + off); off += (size_t)KPAD * DIMEMB * 2;
    unsigned short* WpTt = (unsigned short*)(ws + off); off += (size_t)DIMEMB * DIMIN * 2;
    unsigned short* W1Ts = (unsigned short*)(ws + off); off += (size_t)DIMATTN * DIMEMB * 2;
    float* Tpart = (float*)(ws + off); off += (size_t)3 * KPAD * 4;
    float* Spart = (float*)(ws + off); off += 1024;
    float* Mpart = (float*)(ws + off); off += (size_t)98 * DIMEMB * 4;

    k_prep<<<288, 256, 0, stream>>>(Wproj, W1, WpTt, W1Ts);
    k_gemm1<<<1564, 256, 0, stream>>>(X, WpTt, bproj, H);
    k_gemm2<<<dim3(3, 782), 256, 0, stream>>>(H, W1Ts, b1, W2, Tpart);
    k_poolE<<<98, 512, 0, stream>>>(Tpart, H, b2, Spart, Mpart);
    k_head<<<1, 512, 0, stream>>>(Spart, Mpart, Wr, Xtfl, Wp, bp, out);
}

// Round 17
// 326.000 us; speedup vs baseline: 3.5616x; 3.5616x over previous
//
#include <hip/hip_runtime.h>
#include <hip/hip_bf16.h>

typedef __attribute__((ext_vector_type(8))) short short8_t;
typedef __attribute__((ext_vector_type(4))) float f32x4;
typedef __attribute__((ext_vector_type(4))) unsigned int u32x4;

#define KINST 100000
#define KPAD  100096   // 782 * 128 = 1564 * 64
#define DIMIN 768
#define DIMEMB 512
#define DIMATTN 384

__device__ __forceinline__ unsigned short f2bf(float f) {
    unsigned int u = __builtin_bit_cast(unsigned int, f);
    u = u + 0x7FFFu + ((u >> 16) & 1u);       // RNE
    return (unsigned short)(u >> 16);
}
__device__ __forceinline__ unsigned int packbf(float a, float b) {
    return (unsigned int)f2bf(a) | ((unsigned int)f2bf(b) << 16);
}
__device__ __forceinline__ float bf2f(unsigned short h) {
    unsigned int u = ((unsigned int)h) << 16;
    return __builtin_bit_cast(float, u);
}
__device__ __forceinline__ float fast_tanh(float x) {
    const float e2 = __expf(2.f * x);
    return (e2 - 1.f) * __builtin_amdgcn_rcpf(e2 + 1.f);
}
// async global->LDS, 16B per lane. LDS dest must be wave-uniform base + lane*16.
__device__ __forceinline__ void gll16(const unsigned short* g, unsigned short* l) {
    __builtin_amdgcn_global_load_lds(
        (const __attribute__((address_space(1))) unsigned int*)g,
        (__attribute__((address_space(3))) unsigned int*)l, 16, 0, 0);
}

// ---------------- prep (R9 verified) ----------------
// WpTt (PLAIN): [t<24][n<512][c<4][e<8] = bf16(Wproj[(t*32+c*8+e)*512 + n])
// W1Ts (SWIZZLED): [t<8][n<384][cs<8][e<8], cs = c ^ (n&7) = bf16(W1[(t*64+c*8+e)*384 + n])
__global__ __launch_bounds__(256) void k_prep(
    const float* __restrict__ Wproj, const float* __restrict__ W1,
    unsigned short* __restrict__ WpTt, unsigned short* __restrict__ W1Ts)
{
    const int idx = blockIdx.x * 256 + threadIdx.x;
    if (idx < 49152) {                 // 24*512*4
        const int t = idx >> 11, r = idx & 2047;
        const int n = r >> 2, c = r & 3;
        short8_t v;
        #pragma unroll
        for (int e = 0; e < 8; ++e)
            v[e] = (short)f2bf(Wproj[(size_t)(t * 32 + c * 8 + e) * DIMEMB + n]);
        *(short8_t*)&WpTt[t * 16384 + n * 32 + c * 8] = v;
    } else {
        const int j = idx - 49152;     // < 24576 = 8*8*384
        const int t = j / 3072, r = j % 3072;
        const int c = r / 384, n = r % 384;
        short8_t v;
        #pragma unroll
        for (int e = 0; e < 8; ++e)
            v[e] = (short)f2bf(W1[(size_t)(t * 64 + c * 8 + e) * DIMATTN + n]);
        *(short8_t*)&W1Ts[t * 24576 + n * 64 + ((c ^ (n & 7)) << 3)] = v;
    }
}

// ---------------- GEMM1 (R9 verbatim, 191 us): H = relu(X @ Wp + b); BM=64, BN=512, BK=32 ----------------
// H stored SWIZZLED (R4/R9 format): row*512 + (col>>6)*64 + ((((col>>3)&7)^(row&7))<<3) + (col&7)
__global__ __launch_bounds__(256, 2) void k_gemm1(
    const float* __restrict__ X,
    const unsigned short* __restrict__ WpTt,
    const float* __restrict__ bproj,
    unsigned short* __restrict__ H)
{
    __shared__ unsigned short As[2][2048];   // 64 rows x 32 bf16, granule-XOR
    const int tid = threadIdx.x;
    const int lane = tid & 63, w = tid >> 6;   // 4 waves; wave w -> cols w*128..+127
    const int g = lane >> 4, fr = lane & 15;
    const int brow = blockIdx.x * 64;

    // A staging: thread -> row tid>>2 (0..63), k-granule tid&3 (8 fp32 = 32B), coalesced
    const int arow = tid >> 2, aq4 = tid & 3;
    int agr = brow + arow; if (agr >= KINST) agr = KINST - 1;
    const float* xsrc = X + (size_t)agr * DIMIN + aq4 * 8;
    const int awoff = arow * 32 + ((aq4 ^ ((arow >> 1) & 3)) << 3);
    const int aro = (g ^ ((fr >> 1) & 3)) << 3;   // frag read slot (verified, 0 conflicts)

    // B: per-lane frag base; frag j at + j*512; step t at + t*16384
    const unsigned short* gB = WpTt + (size_t)(w * 128 + fr) * 32 + g * 8;

    f32x4 acc[4][8] = {};
    short8_t Bf[2][8];
    float4 xva, xvb;

    // ---- prologue: X(0)->As[0]; B(0)->Bf[0]; X(1)->regs ----
    {
        float4 xa = *(const float4*)(xsrc);
        float4 xb = *(const float4*)(xsrc + 4);
        #pragma unroll
        for (int j = 0; j < 8; ++j)
            Bf[0][j] = *(const short8_t*)(gB + j * 512);
        xva = *(const float4*)(xsrc + 32);
        xvb = *(const float4*)(xsrc + 36);
        u32x4 p;
        p[0] = packbf(xa.x, xa.y); p[1] = packbf(xa.z, xa.w);
        p[2] = packbf(xb.x, xb.y); p[3] = packbf(xb.z, xb.w);
        *(u32x4*)&As[0][awoff] = p;
    }
    asm volatile("s_waitcnt lgkmcnt(0)" ::: "memory");
    __builtin_amdgcn_sched_barrier(0);
    __builtin_amdgcn_s_barrier();
    __builtin_amdgcn_sched_barrier(0);

#define G1STEP(P, T)                                                           \
    {                                                                          \
        if ((T) < 23) {   /* issue B(T+1) -> Bf[P^1]; consumed NEXT step */    \
            const unsigned short* gBt = gB + (size_t)((T) + 1) * 16384;        \
            _Pragma("unroll")                                                  \
            for (int j = 0; j < 8; ++j)                                        \
                Bf[(P) ^ 1][j] = *(const short8_t*)(gBt + j * 512);            \
        }                                                                      \
        short8_t af[4];   /* A frags from As[P] (ds_read) */                   \
        _Pragma("unroll")                                                      \
        for (int i = 0; i < 4; ++i)                                            \
            af[i] = *(const short8_t*)&As[P][(i * 16 + fr) * 32 + aro];        \
        if ((T) < 23) {   /* convert X(T+1) -> As[P^1]; implicit vmcnt wait    \
                             here also retires B(T) (FIFO) */                  \
            u32x4 p;                                                           \
            p[0] = packbf(xva.x, xva.y); p[1] = packbf(xva.z, xva.w);          \
            p[2] = packbf(xvb.x, xvb.y); p[3] = packbf(xvb.z, xvb.w);          \
            *(u32x4*)&As[(P) ^ 1][awoff] = p;                                  \
        }                                                                      \
        if ((T) < 22) {   /* issue X(T+2); rides the barrier */                \
            xva = *(const float4*)(xsrc + ((T) + 2) * 32);                     \
            xvb = *(const float4*)(xsrc + ((T) + 2) * 32 + 4);                 \
        }                                                                      \
        asm volatile("s_waitcnt lgkmcnt(0)" ::: "memory");                     \
        __builtin_amdgcn_sched_barrier(0);                                     \
        __builtin_amdgcn_s_barrier();                                          \
        __builtin_amdgcn_sched_barrier(0);                                     \
        __builtin_amdgcn_s_setprio(1);                                        \
        _Pragma("unroll")                                                      \
        for (int j = 0; j < 8; ++j)                                            \
            _Pragma("unroll")                                                  \
            for (int i = 0; i < 4; ++i)                                        \
                acc[i][j] = __builtin_amdgcn_mfma_f32_16x16x32_bf16(           \
                    af[i], Bf[P][j], acc[i][j], 0, 0, 0);                      \
        __builtin_amdgcn_s_setprio(0);                                        \
    }

    for (int tt = 0; tt < 24; tt += 2) {
        G1STEP(0, tt);
        G1STEP(1, tt + 1);
    }
#undef G1STEP

    // ---- epilogue: bias + relu, SWIZZLED bf16 H store ----
    #pragma unroll
    for (int j = 0; j < 8; ++j) {
        const int col = w * 128 + j * 16 + fr;
        const float bias = bproj[col];
        const int tile = (col >> 6) << 6, cc = (col >> 3) & 7, lo = col & 7;
        #pragma unroll
        for (int i = 0; i < 4; ++i) {
            const int rb = brow + i * 16 + g * 4;
            #pragma unroll
            for (int r = 0; r < 4; ++r) {
                const int row = rb + r;
                const float v = fmaxf(acc[i][j][r] + bias, 0.f);
                H[(size_t)row * DIMEMB + tile + ((cc ^ (row & 7)) << 3) + lo] =
                    (row < KINST) ? f2bf(v) : (unsigned short)0;
            }
        }
    }
}

// -------- GEMM2 partial scores (R4/R9 verified) + XCD-grouping swizzle --------
// 1-D grid of 8*294 blocks. Under round-robin dispatch, x = bid&7 is the XCD;
// XCD x owns row-groups [x*98, x*98+98). The 3 column-siblings (cb=0..2) of each
// row-group are consecutive y with the SAME x -> same XCD L2 -> H slice fetched once.
__global__ __launch_bounds__(256) void k_gemm2(
    const unsigned short* __restrict__ H,
    const unsigned short* __restrict__ W1Ts,
    const float* __restrict__ b1,
    const float* __restrict__ W2,
    float* __restrict__ Tpart)
{
    const int x = blockIdx.x & 7, y = blockIdx.x >> 3;   // y < 294
    const int rowgrp = x * 98 + y / 3;
    const int cb = y % 3;                                 // 0..2
    if (rowgrp >= 782) return;                            // uniform per block
    const int brow = rowgrp * 128;
    const int bcol = cb * 128;

    __shared__ unsigned short As[2][8192];
    __shared__ unsigned short Bs[2][8192];
    __shared__ float sred[2][128];
    const int tid = threadIdx.x;
    const int lane = tid & 63, w = tid >> 6;
    const int wr = w >> 1, wc = w & 1;
    const int g = lane >> 4, fr = lane & 15;

    const unsigned short* gA = H + (size_t)(brow + w * 32 + (lane >> 3)) * DIMEMB + (lane & 7) * 8;
    const unsigned short* gB = W1Ts + (size_t)(bcol + w * 32 + (lane >> 3)) * 64 + (lane & 7) * 8;
    const int loff = w * 2048 + lane * 8;

    f32x4 acc[4][4] = {};

    #pragma unroll
    for (int q = 0; q < 4; ++q) {
        gll16(gA + q * 4096, &As[0][loff + q * 512]);
        gll16(gB + q * 512,  &Bs[0][loff + q * 512]);
    }
    __syncthreads();

    for (int t = 0; t < 8; ++t) {
        const int buf = t & 1;
        if (t < 7) {
            #pragma unroll
            for (int q = 0; q < 4; ++q) {
                gll16(gA + (t + 1) * 64 + q * 4096,           &As[buf ^ 1][loff + q * 512]);
                gll16(gB + (size_t)(t + 1) * 24576 + q * 512, &Bs[buf ^ 1][loff + q * 512]);
            }
        }
        __builtin_amdgcn_s_setprio(1);
        #pragma unroll
        for (int kk = 0; kk < 2; ++kk) {
            short8_t af[4];
            #pragma unroll
            for (int i = 0; i < 4; ++i) {
                const int row = wr * 64 + i * 16 + fr;
                af[i] = *(const short8_t*)&As[buf][row * 64 + (((kk * 4 + g) ^ (fr & 7)) << 3)];
            }
            #pragma unroll
            for (int j = 0; j < 4; ++j) {
                const int rowb = wc * 64 + j * 16 + fr;
                const short8_t bf = *(const short8_t*)&Bs[buf][rowb * 64 + (((kk * 4 + g) ^ (fr & 7)) << 3)];
                #pragma unroll
                for (int i = 0; i < 4; ++i)
                    acc[i][j] = __builtin_amdgcn_mfma_f32_16x16x32_bf16(af[i], bf, acc[i][j], 0, 0, 0);
            }
        }
        __builtin_amdgcn_s_setprio(0);
        if (t < 7) __syncthreads();
    }

    float ps[4][4] = {};
    #pragma unroll
    for (int j = 0; j < 4; ++j) {
        const int col = bcol + wc * 64 + j * 16 + fr;
        const float bb = b1[col], ww = W2[col];
        #pragma unroll
        for (int i = 0; i < 4; ++i)
            #pragma unroll
            for (int r = 0; r < 4; ++r)
                ps[i][r] += fast_tanh(acc[i][j][r] + bb) * ww;
    }
    #pragma unroll
    for (int off = 1; off < 16; off <<= 1)
        #pragma unroll
        for (int i = 0; i < 4; ++i)
            #pragma unroll
            for (int r = 0; r < 4; ++r)
                ps[i][r] += __shfl_xor(ps[i][r], off, 64);
    if (fr == 0) {
        #pragma unroll
        for (int i = 0; i < 4; ++i)
            #pragma unroll
            for (int r = 0; r < 4; ++r)
                sred[wc][wr * 64 + i * 16 + g * 4 + r] = ps[i][r];
    }
    __syncthreads();
    if (tid < 128)
        Tpart[(size_t)cb * KPAD + brow + tid] = sred[0][tid] + sred[1][tid];
}

// ---------------- poolE (R4/R9 verified, swizzled H) ----------------
__global__ __launch_bounds__(512) void k_poolE(
    const float* __restrict__ Tpart,
    const unsigned short* __restrict__ H,
    const float* __restrict__ b2,
    float* __restrict__ Spart,
    float* __restrict__ Mpart)
{
    __shared__ float Elds[1024];
    __shared__ float red[8][512];
    __shared__ float ssum[8];
    const int tid = threadIdx.x, lane = tid & 63, w = tid >> 6;
    const int base = blockIdx.x * 1024;
    const float bb = b2[0];
    float es = 0.f;
    #pragma unroll
    for (int u = 0; u < 2; ++u) {
        const int r = base + u * 512 + tid;
        float e = 0.f;
        if (r < KINST)
            e = __expf(Tpart[r] + Tpart[KPAD + r] + Tpart[2 * KPAD + r] + bb);
        Elds[u * 512 + tid] = e;
        es += e;
    }
    #pragma unroll
    for (int off = 1; off < 64; off <<= 1) es += __shfl_xor(es, off, 64);
    if (lane == 0) ssum[w] = es;
    __syncthreads();
    if (tid == 0) {
        float t = 0.f;
        #pragma unroll
        for (int i = 0; i < 8; ++i) t += ssum[i];
        Spart[blockIdx.x] = t;
    }

    float pa[8] = {};
    const int tile = (lane >> 3) << 6, cf = lane & 7;
    for (int i = 0; i < 128; ++i) {
        const int lr = i * 8 + w;
        const float e = Elds[lr];
        if (e != 0.f) {                       // wave-uniform; guards OOB rows
            const int r = base + lr;
            const short8_t v = *(const short8_t*)(H + (size_t)r * DIMEMB + tile + ((cf ^ (r & 7)) << 3));
            #pragma unroll
            for (int j = 0; j < 8; ++j) pa[j] += e * bf2f((unsigned short)v[j]);
        }
    }
    #pragma unroll
    for (int j = 0; j < 8; ++j) red[w][lane * 8 + j] = pa[j];
    __syncthreads();
    float s2 = 0.f;
    #pragma unroll
    for (int k = 0; k < 8; ++k) s2 += red[k][tid];
    Mpart[(size_t)blockIdx.x * DIMEMB + tid] = s2;
}

// ---------------- head (R4/R9 verified) ----------------
__global__ __launch_bounds__(512) void k_head(
    const float* __restrict__ Spart,   // [98]
    const float* __restrict__ Mpart,   // [98][512]
    const float* __restrict__ Wr,      // [512][13]
    const float* __restrict__ Xtfl,    // [13][512]
    const float* __restrict__ Wp,      // [512][2]
    const float* __restrict__ bp,      // [2]
    float* __restrict__ outp)
{
    __shared__ float Mlds[512];
    __shared__ float logits[13];
    __shared__ float wsel[5];
    __shared__ int isel[5];
    __shared__ float Slds;
    __shared__ float swred[8];
    __shared__ float r0s[8], r1s[8];
    const int tid = threadIdx.x, lane = tid & 63, w = tid >> 6;

    float s = 0.f;
    if (tid < 98) s = Spart[tid];
    #pragma unroll
    for (int off = 1; off < 64; off <<= 1) s += __shfl_xor(s, off, 64);
    if (lane == 0) swred[w] = s;

    float m = 0.f;
    #pragma unroll 2
    for (int b = 0; b < 98; ++b) m += Mpart[(size_t)b * 512 + tid];

    __syncthreads();
    if (tid == 0) {
        float t = 0.f;
        #pragma unroll
        for (int i = 0; i < 8; ++i) t += swred[i];
        Slds = t;
    }
    __syncthreads();
    Mlds[tid] = m / Slds;
    __syncthreads();
    if (tid < 13) {
        float l = 0.f;
        for (int dd = 0; dd < 512; ++dd) l += Mlds[dd] * Wr[dd * 13 + tid];
        logits[tid] = l;
    }
    __syncthreads();
    if (tid == 0) {
        float mx = -1e30f;
        for (int i = 0; i < 13; ++i) mx = fmaxf(mx, logits[i]);
        float pe[13]; float sum = 0.f;
        for (int i = 0; i < 13; ++i) { pe[i] = __expf(logits[i] - mx); sum += pe[i]; }
        unsigned used = 0;
        for (int t = 0; t < 5; ++t) {
            int bi = 0; float bv = -1.f;
            for (int i = 0; i < 13; ++i)
                if (!((used >> i) & 1u) && pe[i] > bv) { bv = pe[i]; bi = i; }
            used |= (1u << bi);
            wsel[t] = bv / sum;
            isel[t] = bi;
        }
    }
    __syncthreads();
    float mo = 0.f;
    #pragma unroll
    for (int t = 0; t < 5; ++t) mo += wsel[t] * Xtfl[isel[t] * 512 + tid];
    float p0 = mo * Wp[tid * 2 + 0];
    float p1 = mo * Wp[tid * 2 + 1];
    #pragma unroll
    for (int off = 1; off < 64; off <<= 1) {
        p0 += __shfl_xor(p0, off, 64);
        p1 += __shfl_xor(p1, off, 64);
    }
    if (lane == 0) { r0s[w] = p0; r1s[w] = p1; }
    __syncthreads();
    if (tid == 0) {
        float a = bp[0], b = bp[1];
        for (int i = 0; i < 8; ++i) { a += r0s[i]; b += r1s[i]; }
        outp[0] = a; outp[1] = b;
    }
}

extern "C" void kernel_launch(void* const* d_in, const int* in_sizes, int n_in,
                              void* d_out, int out_size, void* d_ws, size_t ws_size,
                              hipStream_t stream)
{
    const float* Xtfl  = (const float*)d_in[0];
    const float* X     = (const float*)d_in[1];
    const float* Wproj = (const float*)d_in[2];
    const float* bproj = (const float*)d_in[3];
    const float* W1    = (const float*)d_in[4];
    const float* b1    = (const float*)d_in[5];
    const float* W2    = (const float*)d_in[6];
    const float* b2    = (const float*)d_in[7];
    const float* Wr    = (const float*)d_in[8];
    const float* Wp    = (const float*)d_in[9];
    const float* bp    = (const float*)d_in[10];
    float* out = (float*)d_out;

    // ws layout (~105 MiB total)
    char* ws = (char*)d_ws;
    size_t off = 0;
    unsigned short* H    = (unsigned short*)(ws + off); off += (size_t)KPAD * DIMEMB * 2;
    unsigned short* WpTt = (unsigned short*)(ws + off); off += (size_t)DIMEMB * DIMIN * 2;
    unsigned short* W1Ts = (unsigned short*)(ws + off); off += (size_t)DIMATTN * DIMEMB * 2;
    float* Tpart = (float*)(ws + off); off += (size_t)3 * KPAD * 4;
    float* Spart = (float*)(ws + off); off += 1024;
    float* Mpart = (float*)(ws + off); off += (size_t)98 * DIMEMB * 4;

    k_prep<<<288, 256, 0, stream>>>(Wproj, W1, WpTt, W1Ts);
    k_gemm1<<<1564, 256, 0, stream>>>(X, WpTt, bproj, H);
    k_gemm2<<<2352, 256, 0, stream>>>(H, W1Ts, b1, W2, Tpart);   // 8 XCD groups x 294
    k_poolE<<<98, 512, 0, stream>>>(Tpart, H, b2, Spart, Mpart);
    k_head<<<1, 512, 0, stream>>>(Spart, Mpart, Wr, Xtfl, Wp, bp, out);
}